// Round 6
// baseline (69.269 us; speedup 1.0000x reference)
//
#include <hip/hip_runtime.h>

// Problem constants
#define DMODEL 256
#define HEADS 8
#define DHEAD 32
#define NSEQ 2048
#define BATCH 4
#define MTOT (BATCH*NSEQ)   // 8192

typedef __bf16 bf16x8 __attribute__((ext_vector_type(8)));
typedef float f32x4 __attribute__((ext_vector_type(4)));

// scale * log2(e): softmax_e(s/sqrt(32)) == softmax_2(s * CS)
#define CS 0.25507282111989365f

__device__ __forceinline__ unsigned short f2bf(float f) {
    union { float f; unsigned int u; } v; v.f = f;
    unsigned int u = v.u;
    unsigned int r = u + 0x7FFFu + ((u >> 16) & 1u);   // RNE
    return (unsigned short)(r >> 16);
}

__device__ __forceinline__ unsigned pkbf(float a, float b) {
    union { __bf16 h[2]; unsigned u; } t;
    t.h[0] = (__bf16)a; t.h[1] = (__bf16)b;
    return t.u;
}

__device__ __forceinline__ f32x4 mfma16(bf16x8 a, bf16x8 b, f32x4 c) {
    return __builtin_amdgcn_mfma_f32_16x16x32_bf16(a, b, c, 0, 0, 0);
}

#define GLD16(g, l) __builtin_amdgcn_global_load_lds( \
    (const __attribute__((address_space(1))) unsigned int*)(g), \
    (__attribute__((address_space(3))) unsigned int*)(l), 16, 0, 0)

// ---------------------------------------------------------------------------
// prep: x -> bf16, weights -> bf16 transposed Wt[n][k], biases -> concat fp32,
// Abuf[384][256] = rows 0-255: Wo row-major; row 256: bo; rows 257-383: 0
// (A-operand for the Woc = Wo@Wc precompute, bias folded as extra row).
// ---------------------------------------------------------------------------
__global__ __launch_bounds__(256) void prep_kernel(
    const float* __restrict__ x,
    const float* __restrict__ Wq, const float* __restrict__ Wk,
    const float* __restrict__ Wv, const float* __restrict__ Wo,
    const float* __restrict__ Wc,
    const float* __restrict__ bq, const float* __restrict__ bk,
    const float* __restrict__ bv, const float* __restrict__ bo,
    const float* __restrict__ bc,
    unsigned short* __restrict__ xbf,   // [8192][256]
    unsigned short* __restrict__ Wt,    // [1280][256]
    float* __restrict__ bcat,           // [1280]
    unsigned short* __restrict__ Abuf)  // [384][256]
{
    int idx = blockIdx.x * 256 + threadIdx.x;
    const int nx4 = (MTOT * DMODEL) / 4;        // 524288
    if (idx < nx4) {
        float4 v = reinterpret_cast<const float4*>(x)[idx];
        ushort4 o;
        o.x = f2bf(v.x); o.y = f2bf(v.y); o.z = f2bf(v.z); o.w = f2bf(v.w);
        reinterpret_cast<ushort4*>(xbf)[idx] = o;
        return;
    }
    int t = idx - nx4;
    if (t < 1280 * 256) {                        // weight transpose
        int n = t >> 8, k = t & 255;
        const float* Wsrc; int col;
        if (n < 256)       { Wsrc = Wq; col = n; }
        else if (n < 512)  { Wsrc = Wk; col = n - 256; }
        else if (n < 768)  { Wsrc = Wv; col = n - 512; }
        else if (n < 1024) { Wsrc = Wo; col = n - 768; }
        else               { Wsrc = Wc; col = n - 1024; }
        Wt[t] = f2bf(Wsrc[k * 256 + col]);
        return;
    }
    t -= 1280 * 256;
    if (t < 1280) {
        float v;
        if (t < 256)       v = bq[t];
        else if (t < 512)  v = bk[t - 256];
        else if (t < 768)  v = bv[t - 512];
        else if (t < 1024) v = bo[t - 768];
        else               v = bc[t - 1024];
        bcat[t] = v;
        return;
    }
    t -= 1280;
    if (t < 384 * 256) {
        int nrow = t >> 8, k = t & 255;
        float v = 0.f;
        if (nrow < 256)       v = Wo[nrow * 256 + k];
        else if (nrow == 256) v = bo[k];
        Abuf[t] = f2bf(v);
    }
}

// ---------------------------------------------------------------------------
// GEMM: out = A @ W + bias, W given as Wt[n][k] bf16, staged in LDS
// (XOR-swizzled 16B blocks via pre-swizzled global_load_lds source).
// Per wave: 32 rows x 64 cols (2x4 acc, 8 MFMA / k-step).
// MODE 0: QKV -> Q (PRE-SCALED by CS), K, Vt
// MODE 2: out fp32 = residual + acc + bias
// MODE 3: Woc precompute: rows<256 -> outQ = Woc^T bf16 [gc][m];
//         row 256 -> outF[gc] = acc + bias[gc]  (boc = bo@Wc + bc)
// ---------------------------------------------------------------------------
template<int MODE, int WM>
__global__ __launch_bounds__(WM * 64) void gemm32(
    const unsigned short* __restrict__ A,
    const unsigned short* __restrict__ Wt,
    const float* __restrict__ bias,
    const float* __restrict__ xres,
    unsigned short* __restrict__ outQ,
    unsigned short* __restrict__ outK,
    unsigned short* __restrict__ outVt,
    float* __restrict__ outF)
{
    __shared__ __align__(16) unsigned short Bl[64 * 256];   // 32 KB
    const int tid = threadIdx.x;
    const int wid = tid >> 6;
    const int lane = tid & 63;
    const int lo = lane & 15, hi = lane >> 4;
    const int m0 = blockIdx.x * (WM * 32) + wid * 32;
    const int n0 = blockIdx.y * 64;

    const int NCALL = 2048 / (WM * 64);
#pragma unroll
    for (int j = 0; j < NCALL; ++j) {
        int chunkbase = (j * WM + wid) * 64;
        int chunk = chunkbase + lane;
        int row = chunk >> 5, Jp = chunk & 31;
        int J = (Jp & 24) | ((Jp ^ row) & 7);
        GLD16(Wt + (n0 + row) * 256 + J * 8, Bl + chunkbase * 8);
    }
    asm volatile("s_waitcnt vmcnt(0)" ::: "memory");
    __syncthreads();

    const unsigned short* arow0 = A + (m0 + lo) * 256 + hi * 8;
    f32x4 acc[2][4] = {};
#pragma unroll
    for (int s = 0; s < 8; ++s) {
        bf16x8 a0 = *reinterpret_cast<const bf16x8*>(arow0 + s * 32);
        bf16x8 a1 = *reinterpret_cast<const bf16x8*>(arow0 + 16 * 256 + s * 32);
        int Jp = ((s >> 1) << 3) | ((((s & 1) << 2) + hi) ^ (lo & 7));
#pragma unroll
        for (int n = 0; n < 4; ++n) {
            bf16x8 b = *reinterpret_cast<const bf16x8*>(
                Bl + (n * 16 + lo) * 256 + Jp * 8);
            acc[0][n] = mfma16(a0, b, acc[0][n]);
            acc[1][n] = mfma16(a1, b, acc[1][n]);
        }
    }
#pragma unroll
    for (int mf = 0; mf < 2; ++mf) {
        const int row_base = m0 + mf * 16 + hi * 4;
#pragma unroll
        for (int n = 0; n < 4; ++n) {
            int gc = n0 + n * 16 + lo;
            float bs = (MODE == 3) ? 0.0f : bias[gc];
#pragma unroll
            for (int i = 0; i < 4; ++i) {
                int m = row_base + i;
                float val = acc[mf][n][i] + bs;
                if (MODE == 0) {
                    int b = m >> 11, nn = m & 2047;
                    int which = gc >> 8, hh = (gc >> 5) & 7, dh = gc & 31;
                    if (which == 0)
                        outQ[(((b * 8) + hh) * 2048 + nn) * 32 + dh] = f2bf(val * CS);
                    else if (which == 1)
                        outK[(((b * 8) + hh) * 2048 + nn) * 32 + dh] = f2bf(val);
                    else
                        outVt[(((b * 8) + hh) * 32 + dh) * 2048 + nn] = f2bf(val);
                } else if (MODE == 2) {
                    outF[m * 256 + gc] = xres[m * 256 + gc] + val;
                } else {  // MODE 3
                    if (m < 256)
                        outQ[gc * 256 + m] = f2bf(val);      // Woc^T[n][k]
                    else if (m == 256)
                        outF[gc] = val + bias[gc];           // boc
                }
            }
        }
    }
}

// ---------------------------------------------------------------------------
// Flash attention v3: no-max softmax, P in-register (permlane redistribute),
// split-KV: 512-thread blocks, waves 0-3 keys [0,1024), waves 4-7 [1024,2048)
// for the same 64 q-rows; partials combined via LDS (pure addition).
// K staged with conflict-free slot swizzle via pre-swizzled global source;
// V staged with j^=row&7 swizzle. Double-buffered per half. setprio(1)
// around the compute cluster (T5: multiple free-running blocks per CU).
// ---------------------------------------------------------------------------
__global__ __launch_bounds__(512, 8) void attn_kernel(
    const unsigned short* __restrict__ Q,    // [32][2048][32] bf16 (pre-scaled)
    const unsigned short* __restrict__ K,    // [32][2048][32] bf16
    const unsigned short* __restrict__ Vt,   // [32][32][2048] bf16
    unsigned short* __restrict__ ctx)        // [8192][256] bf16 (heads merged)
{
    __shared__ __align__(16) char smem[32768];

    const int tid = threadIdx.x;
    const int wid = tid >> 6;          // 0..7
    const int lane = tid & 63;
    const int lo = lane & 15, hi = lane >> 4;
    const int half = wid >> 2;         // KV half
    const int qw = wid & 3;            // q sub-tile

    // XCD-swizzled decode: bid = 8*(qt + 32*g) + r, bh = g*8+r
    const int bid = blockIdx.x;
    const int bh = ((bid >> 8) << 3) | (bid & 7);
    const int qt = (bid >> 3) & 31;
    const int q0 = qt * 64 + qw * 16;

    const unsigned short* Qb = Q + bh * (NSEQ * 32);
    const unsigned short* Kb = K + bh * (NSEQ * 32);
    const unsigned short* Vb = Vt + bh * (32 * NSEQ);

    bf16x8 qf = *reinterpret_cast<const bf16x8*>(Qb + (q0 + lo) * 32 + hi * 8);

    const int lt = tid & 255;
    const int kbase = half * 1024;
    const unsigned short* ksrc = Kb + (kbase + 2 * (lt >> 3) + ((lt >> 2) & 1)) * 32
                                    + ((lt & 3) ^ ((lt >> 3) & 3)) * 8;
    const unsigned short* vsrc = Vb + (lt >> 3) * NSEQ + kbase
                                    + (((lt & 7) ^ ((lt >> 3) & 7)) * 8);
    char* Kd0 = smem + (half * 2) * 4096 + lt * 16;
    char* Kd1 = smem + (half * 2 + 1) * 4096 + lt * 16;
    char* Vd0 = smem + 16384 + (half * 2) * 4096 + lt * 16;
    char* Vd1 = smem + 16384 + (half * 2 + 1) * 4096 + lt * 16;

    f32x4 o0 = {}, o1 = {}, od = {};
    const int prs = lo & 7;
    const int kxor = (hi ^ ((lo >> 1) & 3)) * 8;   // K read swizzle (ushorts)

    union { unsigned u[4]; bf16x8 v; } ones;
    ones.u[0] = 0x3F803F80u; ones.u[1] = 0x3F803F80u;
    ones.u[2] = 0x3F803F80u; ones.u[3] = 0x3F803F80u;

    GLD16(ksrc, Kd0);
    GLD16(vsrc, Vd0);
    asm volatile("s_waitcnt vmcnt(0)" ::: "memory");
    __builtin_amdgcn_s_barrier();
    __builtin_amdgcn_sched_barrier(0);

    int cur = 0;
    for (int t = 0; t < 16; ++t) {
        if (t < 15) {   // prefetch next tile (uniform branch)
            GLD16(ksrc + (t + 1) * 2048, cur ? Kd0 : Kd1);
            GLD16(vsrc + (t + 1) * 64,   cur ? Vd0 : Vd1);
        }
        const unsigned short* Kc =
            (const unsigned short*)(smem + (half * 2 + cur) * 4096);
        const unsigned short* Vc =
            (const unsigned short*)(smem + 16384 + (half * 2 + cur) * 4096);

        __builtin_amdgcn_s_setprio(1);
        // S^T = K Q^T : lane holds S[k=16c+4hi+i][q=q0+lo]
        f32x4 s[4];
#pragma unroll
        for (int c = 0; c < 4; ++c) {
            bf16x8 kf = *reinterpret_cast<const bf16x8*>(
                Kc + (c * 16 + lo) * 32 + kxor);
            f32x4 z = {};
            s[c] = mfma16(kf, qf, z);
        }
        // P = exp2(S); redistribute in-register to PV B-frag layout
#pragma unroll
        for (int kk = 0; kk < 2; ++kk) {
            const f32x4 s0 = s[2 * kk], s1 = s[2 * kk + 1];
            unsigned uA = pkbf(__builtin_amdgcn_exp2f(s0[0]),
                               __builtin_amdgcn_exp2f(s0[1]));
            unsigned uB = pkbf(__builtin_amdgcn_exp2f(s0[2]),
                               __builtin_amdgcn_exp2f(s0[3]));
            unsigned uC = pkbf(__builtin_amdgcn_exp2f(s1[0]),
                               __builtin_amdgcn_exp2f(s1[1]));
            unsigned uD = pkbf(__builtin_amdgcn_exp2f(s1[2]),
                               __builtin_amdgcn_exp2f(s1[3]));
            auto r1 = __builtin_amdgcn_permlane32_swap(uA, uC, false, false);
            auto r2 = __builtin_amdgcn_permlane16_swap(r1[0], r1[1], false, false);
            auto r3 = __builtin_amdgcn_permlane32_swap(uB, uD, false, false);
            auto r4 = __builtin_amdgcn_permlane16_swap(r3[0], r3[1], false, false);
            union { unsigned u[4]; bf16x8 v; } pb;
            pb.u[0] = r2[0]; pb.u[1] = r4[0]; pb.u[2] = r2[1]; pb.u[3] = r4[1];

            int sw = ((4 * kk + hi) ^ prs) << 3;
            bf16x8 a0 = *reinterpret_cast<const bf16x8*>(Vc + lo * 64 + sw);
            bf16x8 a1 = *reinterpret_cast<const bf16x8*>(Vc + (16 + lo) * 64 + sw);
            o0 = mfma16(a0, pb.v, o0);
            o1 = mfma16(a1, pb.v, o1);
            od = mfma16(ones.v, pb.v, od);   // denominator rows
        }
        __builtin_amdgcn_s_setprio(0);
        asm volatile("s_waitcnt vmcnt(0)" ::: "memory");
        __builtin_amdgcn_s_barrier();
        __builtin_amdgcn_sched_barrier(0);
        cur ^= 1;
    }

    // combine halves: pure addition (no-max softmax partials)
    float* comb = (float*)smem;                 // [4][64][12]
    const int cidx = (qw * 64 + lane) * 12;
    __syncthreads();
    if (wid >= 4) {
        *reinterpret_cast<f32x4*>(comb + cidx)     = o0;
        *reinterpret_cast<f32x4*>(comb + cidx + 4) = o1;
        comb[cidx + 8] = od[0];
    }
    __syncthreads();
    if (wid < 4) {
        f32x4 p0 = *reinterpret_cast<const f32x4*>(comb + cidx);
        f32x4 p1 = *reinterpret_cast<const f32x4*>(comb + cidx + 4);
        float dsum = od[0] + comb[cidx + 8];
        o0 += p0; o1 += p1;
        float inv = 1.0f / dsum;

        const int b = bh >> 3, h = bh & 7;
        unsigned short* dst = ctx + (size_t)((b * 2048 + q0 + lo)) * 256 + h * 32;
        ushort4 w0, w1;
        w0.x = f2bf(o0[0] * inv); w0.y = f2bf(o0[1] * inv);
        w0.z = f2bf(o0[2] * inv); w0.w = f2bf(o0[3] * inv);
        w1.x = f2bf(o1[0] * inv); w1.y = f2bf(o1[1] * inv);
        w1.z = f2bf(o1[2] * inv); w1.w = f2bf(o1[3] * inv);
        *reinterpret_cast<ushort4*>(dst + hi * 4)      = w0;
        *reinterpret_cast<ushort4*>(dst + 16 + hi * 4) = w1;
    }
}

// ---------------------------------------------------------------------------
extern "C" void kernel_launch(void* const* d_in, const int* in_sizes, int n_in,
                              void* d_out, int out_size, void* d_ws, size_t ws_size,
                              hipStream_t stream) {
    const float* x  = (const float*)d_in[0];
    const float* Wq = (const float*)d_in[1];
    const float* bq = (const float*)d_in[2];
    const float* Wk = (const float*)d_in[3];
    const float* bk = (const float*)d_in[4];
    const float* Wv = (const float*)d_in[5];
    const float* bv = (const float*)d_in[6];
    const float* Wo = (const float*)d_in[7];
    const float* bo = (const float*)d_in[8];
    const float* Wc = (const float*)d_in[9];
    const float* bc = (const float*)d_in[10];
    float* out = (float*)d_out;

    char* p = (char*)d_ws;
    unsigned short* xbf  = (unsigned short*)p;  p += (size_t)MTOT * DMODEL * 2;   // 4 MB
    unsigned short* Wt   = (unsigned short*)p;  p += (size_t)1280 * 256 * 2;      // 640 KB
    float* bcat          = (float*)p;           p += (size_t)1280 * 4;            // 5 KB
    unsigned short* Qw   = (unsigned short*)p;  p += (size_t)32 * 2048 * 32 * 2;  // 4 MB
    unsigned short* Kw   = (unsigned short*)p;  p += (size_t)32 * 2048 * 32 * 2;  // 4 MB
    unsigned short* Vtw  = (unsigned short*)p;  p += (size_t)32 * 32 * 2048 * 2;  // 4 MB
    unsigned short* ctx  = (unsigned short*)p;  p += (size_t)MTOT * DMODEL * 2;   // 4 MB
    unsigned short* Abuf = (unsigned short*)p;  p += (size_t)384 * 256 * 2;       // 192 KB
    unsigned short* Woct = (unsigned short*)p;  p += (size_t)256 * 256 * 2;       // 128 KB
    float* bocf          = (float*)p;           p += (size_t)256 * 4;             // 1 KB

    // prep: 524288 + 327680 + 1280 + 98304 = 951552 threads -> 3717 blocks
    prep_kernel<<<3717, 256, 0, stream>>>(x, Wq, Wk, Wv, Wo, Wc,
                                          bq, bk, bv, bo, bc,
                                          xbf, Wt, bcat, Abuf);
    // Woc = Wo@Wc (rows 0-255), boc = bo@Wc + bc (row 256); B = Wc^T tile
    gemm32<3, 4><<<dim3(3, 4), 256, 0, stream>>>(Abuf, Wt + 1024 * 256, bc,
                                                 nullptr, Woct, nullptr, nullptr, bocf);
    // QKV projection
    gemm32<0, 4><<<dim3(64, 12), 256, 0, stream>>>(xbf, Wt, bcat, nullptr,
                                                   Qw, Kw, Vtw, nullptr);
    // attention
    attn_kernel<<<1024, 512, 0, stream>>>(Qw, Kw, Vtw, ctx);
    // fused output+context projection + residual: out = x + ctx@Woc + boc
    gemm32<2, 4><<<dim3(64, 4), 256, 0, stream>>>(ctx, Woct, bocf,
                                                  x, nullptr, nullptr, nullptr, out);
}